// Round 4
// baseline (285.491 us; speedup 1.0000x reference)
//
#include <hip/hip_runtime.h>
#include <hip/hip_bf16.h>
#include <stdint.h>

typedef __bf16 bf16_t;
typedef bf16_t bf16x8 __attribute__((ext_vector_type(8)));
typedef bf16_t bf16x4 __attribute__((ext_vector_type(4)));
typedef float f32x4 __attribute__((ext_vector_type(4)));

#define LOG2E 1.44269504088896340736f

// async global->LDS, 16B per lane. Dest must be linear (base + lane*16).
__device__ __forceinline__ void gld16(const void* g, void* l) {
  __builtin_amdgcn_global_load_lds(
      (__attribute__((address_space(1))) void*)(void*)(g),
      (__attribute__((address_space(3))) void*)(l), 16, 0, 0);
}

// XOR swizzle for 128B-row LDS tiles: spreads the 16B column slots across rows.
__device__ __forceinline__ int swz(int byteoff) {
  return byteoff ^ (((byteoff >> 7) & 7) << 4);
}

// ---------------- fp32 -> bf16 convert (fused launches) ----------------
__global__ __launch_bounds__(256) void cvt3_kernel(
    const float* __restrict__ s0, const float* __restrict__ s1, const float* __restrict__ s2,
    bf16_t* __restrict__ d0, bf16_t* __restrict__ d1, bf16_t* __restrict__ d2) {
  const int t = blockIdx.x >> 10;
  const float* s = (t == 0) ? s0 : ((t == 1) ? s1 : s2);
  bf16_t* d = (t == 0) ? d0 : ((t == 1) ? d1 : d2);
  int i = (blockIdx.x & 1023) * 256 + threadIdx.x;
#pragma unroll
  for (int u = 0; u < 8; ++u, i += 1024 * 256) {
    const float4 v = reinterpret_cast<const float4*>(s)[i];
    bf16x4 o;
    o[0] = (bf16_t)v.x; o[1] = (bf16_t)v.y; o[2] = (bf16_t)v.z; o[3] = (bf16_t)v.w;
    reinterpret_cast<bf16x4*>(d)[i] = o;
  }
}

__global__ __launch_bounds__(256) void cvt4_kernel(
    const float* __restrict__ s0, const float* __restrict__ s1,
    const float* __restrict__ s2, const float* __restrict__ s3,
    bf16_t* __restrict__ d0, bf16_t* __restrict__ d1,
    bf16_t* __restrict__ d2, bf16_t* __restrict__ d3) {
  const int t = blockIdx.x >> 7;
  const float* s = (t == 0) ? s0 : ((t == 1) ? s1 : ((t == 2) ? s2 : s3));
  bf16_t* d = (t == 0) ? d0 : ((t == 1) ? d1 : ((t == 2) ? d2 : d3));
  int i = (blockIdx.x & 127) * 256 + threadIdx.x;
#pragma unroll
  for (int u = 0; u < 8; ++u, i += 128 * 256) {
    const float4 v = reinterpret_cast<const float4*>(s)[i];
    bf16x4 o;
    o[0] = (bf16_t)v.x; o[1] = (bf16_t)v.y; o[2] = (bf16_t)v.z; o[3] = (bf16_t)v.w;
    reinterpret_cast<bf16x4*>(d)[i] = o;
  }
}

// ---------------- GEMM: Out = A @ W^T + bias ----------------
#define GBM 128
#define GBN 128
#define GBK 32

template <int MODE>
__global__ __launch_bounds__(256) void gemm_bt(
    const bf16_t* __restrict__ A, const bf16_t* __restrict__ W,
    const float* __restrict__ bias, void* __restrict__ Out,
    int M, int N, int K) {
  __shared__ bf16_t As[GBM * GBK];
  __shared__ bf16_t Bs[GBN * GBK];
  const int tid = threadIdx.x;
  const int lane = tid & 63;
  const int w = tid >> 6;
  const int m0 = blockIdx.x * GBM;
  const int n0 = blockIdx.y * GBN;
  const int wm = (w >> 1) * 64;
  const int wn = (w & 1) * 64;

  f32x4 acc[4][4] = {};

  const int sr = w * 16 + (lane >> 2);
  const int sc = (lane & 3) * 8;
  const bf16_t* Ab = A + (size_t)(m0 + sr) * K + sc;
  const bf16_t* Wb = W + (size_t)(n0 + sr) * K + sc;
  const int rr = lane & 15;
  const int kk8 = (lane >> 4) * 8;

  for (int k0 = 0; k0 < K; k0 += GBK) {
    gld16(Ab + k0, &As[sr * GBK + sc]);
    gld16(Ab + (size_t)64 * K + k0, &As[(sr + 64) * GBK + sc]);
    gld16(Wb + k0, &Bs[sr * GBK + sc]);
    gld16(Wb + (size_t)64 * K + k0, &Bs[(sr + 64) * GBK + sc]);
    __syncthreads();
    bf16x8 a[4], b[4];
#pragma unroll
    for (int i = 0; i < 4; ++i)
      a[i] = *reinterpret_cast<const bf16x8*>(&As[(wm + i * 16 + rr) * GBK + kk8]);
#pragma unroll
    for (int i = 0; i < 4; ++i)
      b[i] = *reinterpret_cast<const bf16x8*>(&Bs[(wn + i * 16 + rr) * GBK + kk8]);
#pragma unroll
    for (int i = 0; i < 4; ++i)
#pragma unroll
      for (int j = 0; j < 4; ++j)
        acc[i][j] = __builtin_amdgcn_mfma_f32_16x16x32_bf16(a[i], b[j], acc[i][j], 0, 0, 0);
    __syncthreads();
  }

  const int rg = (lane >> 4) * 4;
#pragma unroll
  for (int i = 0; i < 4; ++i) {
#pragma unroll
    for (int j = 0; j < 4; ++j) {
      const int col = n0 + wn + j * 16 + rr;
      const float bi = bias[col];
      if (MODE == 3) {
#pragma unroll
        for (int r = 0; r < 4; ++r) {
          const int row = m0 + wm + i * 16 + rg + r;
          reinterpret_cast<float*>(Out)[(size_t)row * N + col] = acc[i][j][r] + bi;
        }
      } else if (MODE == 2) {
        const int row0 = m0 + wm + i * 16 + rg;
        const int b_ = row0 >> 11, s_ = row0 & 2047;
        const int h_ = col >> 6, d_ = col & 63;
        bf16x4 pack;
#pragma unroll
        for (int r = 0; r < 4; ++r) pack[r] = (bf16_t)(acc[i][j][r] + bi);
        bf16_t* O = reinterpret_cast<bf16_t*>(Out);
        *reinterpret_cast<bf16x4*>(&O[((size_t)((b_ * 16 + h_) * 64 + d_)) * 2048 + s_]) = pack;
      } else {
#pragma unroll
        for (int r = 0; r < 4; ++r) {
          const int row = m0 + wm + i * 16 + rg + r;
          const int b_ = row >> 11, s_ = row & 2047;
          const int h_ = col >> 6, d_ = col & 63;
          float v = acc[i][j][r] + bi;
          if (MODE == 0) v *= 0.125f * LOG2E;
          bf16_t* O = reinterpret_cast<bf16_t*>(Out);
          O[((size_t)((b_ * 16 + h_) * 2048 + s_)) * 64 + d_] = (bf16_t)v;
        }
      }
    }
  }
}

// ---------------- flash attention with banded local bias ----------------
// v4: P overlaid on the (dead-after-prologue) Q LDS buffer -> 32.9KB LDS
// -> 4 blocks/CU, and grid (1024) == 256 CU x 4 fully co-resident.
// P uses the same 128B-stride XOR swizzle as K/V (write-side swizzle legal:
// we own both sides). Wave w's P region == wave w's own Q rows, ordering
// guaranteed by the Q->qf->MFMA->P data dependence within the wave.
#define QT 128
#define KT 64

__global__ __launch_bounds__(256) void attn_kernel(
    const bf16_t* __restrict__ Qg, const bf16_t* __restrict__ Kg,
    const bf16_t* __restrict__ Vtg, const float* __restrict__ lb,
    bf16_t* __restrict__ Og) {
  const int S = 2048;
  __shared__ bf16_t QPs[QT * 64];   // 16KB: Q (prologue) then per-wave P (4KB each)
  __shared__ bf16_t Ks[KT * 64];    // 8KB, swizzled
  __shared__ bf16_t Vts[64 * KT];   // 8KB, swizzled (rows=d, cols=k)
  __shared__ float lbs[33];

  const int tid = threadIdx.x, lane = tid & 63, w = tid >> 6;
  const int qt0 = blockIdx.x * QT;
  const int bh = blockIdx.y;
  const int b_ = bh >> 4, h_ = bh & 15;

  const char* Qb = (const char*)(Qg + (size_t)bh * S * 64);
  const char* Kb = (const char*)(Kg + (size_t)bh * S * 64);
  const char* Vtb = (const char*)(Vtg + (size_t)bh * 64 * S);

  const int loff = w * 1024 + lane * 16;
#pragma unroll
  for (int i = 0; i < 4; ++i) {
    const int off = i * 4096 + loff;
    gld16(Qb + (size_t)qt0 * 128 + swz(off), (char*)QPs + off);
  }
  if (tid < 33) lbs[tid] = lb[tid];

  // T14 staging: per-thread 16B chunks; write-side swizzle
  const int L0 = tid * 16;                   // 0..4095
  const int W0 = swz(L0), W1 = swz(L0 + 4096);
  const int vd0 = L0 >> 7, vcb = L0 & 127;   // Vt row/col for chunk 0
  int4 kr0, kr1, vr0, vr1;
  {
    kr0 = *reinterpret_cast<const int4*>(Kb + L0);
    kr1 = *reinterpret_cast<const int4*>(Kb + L0 + 4096);
    vr0 = *reinterpret_cast<const int4*>(Vtb + (size_t)vd0 * 4096 + vcb);
    vr1 = *reinterpret_cast<const int4*>(Vtb + (size_t)(vd0 + 32) * 4096 + vcb);
  }
  __syncthreads();  // Q staged (drains gld16)

  const int rr = lane & 15;
  const int kk8 = (lane >> 4) * 8;
  const int rg = (lane >> 4) * 4;
  char* pb = (char*)QPs + w * 4096;  // this wave's P region (its own Q rows)

  bf16x8 qf[2][2];
#pragma unroll
  for (int qg = 0; qg < 2; ++qg)
#pragma unroll
    for (int kk = 0; kk < 2; ++kk) {
      const int off = (w * 32 + qg * 16 + rr) * 128 + (kk * 32 + kk8) * 2;
      qf[qg][kk] = *reinterpret_cast<const bf16x8*>((const char*)QPs + swz(off));
    }

  f32x4 oacc[2][4] = {};
  float lrowp[2] = {0.f, 0.f};

  for (int kt = 0; kt < S / KT; ++kt) {
    // write staged tile kt to LDS (regs loaded last iter; latency hidden)
    *reinterpret_cast<int4*>((char*)Ks + W0) = kr0;
    *reinterpret_cast<int4*>((char*)Ks + W1) = kr1;
    *reinterpret_cast<int4*>((char*)Vts + W0) = vr0;
    *reinterpret_cast<int4*>((char*)Vts + W1) = vr1;
    // prefetch tile kt+1 (clamped; overlaps this iteration's compute)
    {
      const int ktn = (kt + 1) & 31;
      const char* kp = Kb + (size_t)ktn * 8192;
      kr0 = *reinterpret_cast<const int4*>(kp + L0);
      kr1 = *reinterpret_cast<const int4*>(kp + L0 + 4096);
      const char* vp = Vtb + (size_t)ktn * 128;
      vr0 = *reinterpret_cast<const int4*>(vp + (size_t)vd0 * 4096 + vcb);
      vr1 = *reinterpret_cast<const int4*>(vp + (size_t)(vd0 + 32) * 4096 + vcb);
    }
    __syncthreads();  // tile kt visible

    // QK^T (swapped): lane holds q = qg*16+rr, k = ni*16 + rg + r
    bf16x8 kf[4][2];
#pragma unroll
    for (int ni = 0; ni < 4; ++ni)
#pragma unroll
      for (int kk = 0; kk < 2; ++kk) {
        const int off = (ni * 16 + rr) * 128 + (kk * 32 + kk8) * 2;
        kf[ni][kk] = *reinterpret_cast<const bf16x8*>((const char*)Ks + swz(off));
      }
    f32x4 sc[2][4];
#pragma unroll
    for (int qg = 0; qg < 2; ++qg)
#pragma unroll
      for (int ni = 0; ni < 4; ++ni) {
        f32x4 z = {0.f, 0.f, 0.f, 0.f};
#pragma unroll
        for (int kk = 0; kk < 2; ++kk)
          z = __builtin_amdgcn_mfma_f32_16x16x32_bf16(kf[ni][kk], qf[qg][kk], z, 0, 0, 0);
        sc[qg][ni] = z;
      }

    // banded local bias (exp2 domain)
    const int kbase = kt * KT;
    if (kbase + KT + 16 > qt0 && kbase < qt0 + QT + 16) {
#pragma unroll
      for (int qg = 0; qg < 2; ++qg) {
        const int q = qt0 + w * 32 + qg * 16 + rr;
#pragma unroll
        for (int ni = 0; ni < 4; ++ni)
#pragma unroll
          for (int r = 0; r < 4; ++r) {
            const int rel = (kbase + ni * 16 + rg + r) - q;
            if (rel >= -16 && rel <= 16)
              sc[qg][ni][r] += (2.0f * LOG2E) * lbs[rel + 16];
          }
      }
    }

    // softmax without max subtraction (scores bounded); partial l per lane
#pragma unroll
    for (int qg = 0; qg < 2; ++qg) {
      float ps0 = 0.f, ps1 = 0.f;
#pragma unroll
      for (int ni = 0; ni < 4; ++ni) {
        bf16x4 pk;
        float p0 = exp2f(sc[qg][ni][0]);
        float p1 = exp2f(sc[qg][ni][1]);
        float p2 = exp2f(sc[qg][ni][2]);
        float p3 = exp2f(sc[qg][ni][3]);
        ps0 += p0 + p2;
        ps1 += p1 + p3;
        pk[0] = (bf16_t)p0; pk[1] = (bf16_t)p1; pk[2] = (bf16_t)p2; pk[3] = (bf16_t)p3;
        *reinterpret_cast<bf16x4*>(
            pb + swz((qg * 16 + rr) * 128 + (ni * 16 + rg) * 2)) = pk;
      }
      lrowp[qg] += ps0 + ps1;
    }
    asm volatile("s_waitcnt lgkmcnt(0)" ::: "memory");
    __builtin_amdgcn_sched_barrier(0);

    // PV
#pragma unroll
    for (int kk = 0; kk < 2; ++kk) {
      bf16x8 pf[2], vf[4];
#pragma unroll
      for (int mi = 0; mi < 2; ++mi)
        pf[mi] = *reinterpret_cast<const bf16x8*>(
            pb + swz((mi * 16 + rr) * 128 + (kk * 32 + kk8) * 2));
#pragma unroll
      for (int nd = 0; nd < 4; ++nd) {
        const int off = (nd * 16 + rr) * 128 + (kk * 32 + kk8) * 2;
        vf[nd] = *reinterpret_cast<const bf16x8*>((const char*)Vts + swz(off));
      }
#pragma unroll
      for (int mi = 0; mi < 2; ++mi)
#pragma unroll
        for (int nd = 0; nd < 4; ++nd)
          oacc[mi][nd] = __builtin_amdgcn_mfma_f32_16x16x32_bf16(pf[mi], vf[nd], oacc[mi][nd], 0, 0, 0);
    }
    __syncthreads();  // all waves done reading Ks/Vts before next ds_write
  }

  // epilogue: reduce l across the 4 lane-groups, then divide + store
  float lr[2];
#pragma unroll
  for (int qg = 0; qg < 2; ++qg) {
    float t = lrowp[qg];
    t += __shfl_xor(t, 16, 64);
    t += __shfl_xor(t, 32, 64);
    lr[qg] = t;
  }
#pragma unroll
  for (int mi = 0; mi < 2; ++mi) {
    float lf[4];
#pragma unroll
    for (int r = 0; r < 4; ++r)
      lf[r] = __shfl(lr[mi], (lane & 48) | (rg + r), 64);
#pragma unroll
    for (int nd = 0; nd < 4; ++nd)
#pragma unroll
      for (int r = 0; r < 4; ++r) {
        const int srow = qt0 + w * 32 + mi * 16 + rg + r;
        const int d = nd * 16 + rr;
        const float v = oacc[mi][nd][r] / lf[r];
        Og[((size_t)(b_ * 2048 + srow)) * 1024 + h_ * 64 + d] = (bf16_t)v;
      }
  }
}

// ---------------- launch ----------------
extern "C" void kernel_launch(void* const* d_in, const int* in_sizes, int n_in,
                              void* d_out, int out_size, void* d_ws, size_t ws_size,
                              hipStream_t stream) {
  const float* q32 = (const float*)d_in[0];
  const float* k32 = (const float*)d_in[1];
  const float* v32 = (const float*)d_in[2];
  const float* wq = (const float*)d_in[3];
  const float* bq = (const float*)d_in[4];
  const float* wk = (const float*)d_in[5];
  const float* bk = (const float*)d_in[6];
  const float* wv = (const float*)d_in[7];
  const float* bv = (const float*)d_in[8];
  const float* wo = (const float*)d_in[9];
  const float* bo = (const float*)d_in[10];
  const float* lb = (const float*)d_in[11];

  const int M = 8192, N = 1024, K = 1024;
  const size_t REG = (size_t)M * N * 2;

  char* ws = (char*)d_ws;
  bf16_t* Xq = (bf16_t*)(ws + 0 * REG);
  bf16_t* Xk = (bf16_t*)(ws + 1 * REG);
  bf16_t* Xv = (bf16_t*)(ws + 2 * REG);
  bf16_t* Qb = (bf16_t*)(ws + 3 * REG);
  bf16_t* Wqb = (bf16_t*)(ws + 4 * REG);
  bf16_t* Wkb = Wqb + (size_t)N * K;
  bf16_t* Wvb = Wkb + (size_t)N * K;
  bf16_t* Wob = Wvb + (size_t)N * K;
  bf16_t* Kb = Xq;    // Xq dead after Q-GEMM
  bf16_t* Vt = Xk;    // Xk dead after K-GEMM
  bf16_t* attn = Xv;  // Xv dead after V-GEMM

  cvt3_kernel<<<dim3(3072), dim3(256), 0, stream>>>(q32, k32, v32, Xq, Xk, Xv);
  cvt4_kernel<<<dim3(512), dim3(256), 0, stream>>>(wq, wk, wv, wo, Wqb, Wkb, Wvb, Wob);

  dim3 gg(M / GBM, N / GBN);
  gemm_bt<0><<<gg, 256, 0, stream>>>(Xq, Wqb, bq, Qb, M, N, K);
  gemm_bt<1><<<gg, 256, 0, stream>>>(Xk, Wkb, bk, Kb, M, N, K);
  gemm_bt<2><<<gg, 256, 0, stream>>>(Xv, Wvb, bv, Vt, M, N, K);

  attn_kernel<<<dim3(2048 / QT, 64), 256, 0, stream>>>(Qb, Kb, Vt, lb, attn);

  gemm_bt<3><<<gg, 256, 0, stream>>>(attn, Wob, bo, d_out, M, N, K);
}

// Round 5
// 279.264 us; speedup vs baseline: 1.0223x; 1.0223x over previous
//
#include <hip/hip_runtime.h>
#include <hip/hip_bf16.h>
#include <stdint.h>

typedef __bf16 bf16_t;
typedef bf16_t bf16x8 __attribute__((ext_vector_type(8)));
typedef bf16_t bf16x4 __attribute__((ext_vector_type(4)));
typedef float f32x4 __attribute__((ext_vector_type(4)));

#define LOG2E 1.44269504088896340736f

// async global->LDS, 16B per lane. Dest must be linear (base + lane*16).
__device__ __forceinline__ void gld16(const void* g, void* l) {
  __builtin_amdgcn_global_load_lds(
      (__attribute__((address_space(1))) void*)(void*)(g),
      (__attribute__((address_space(3))) void*)(l), 16, 0, 0);
}

// XOR swizzle for 128B-row LDS tiles: spreads the 16B column slots across rows.
__device__ __forceinline__ int swz(int byteoff) {
  return byteoff ^ (((byteoff >> 7) & 7) << 4);
}

// ---------------- fp32 -> bf16 convert (fused launches) ----------------
__global__ __launch_bounds__(256) void cvt3_kernel(
    const float* __restrict__ s0, const float* __restrict__ s1, const float* __restrict__ s2,
    bf16_t* __restrict__ d0, bf16_t* __restrict__ d1, bf16_t* __restrict__ d2) {
  const int t = blockIdx.x >> 10;
  const float* s = (t == 0) ? s0 : ((t == 1) ? s1 : s2);
  bf16_t* d = (t == 0) ? d0 : ((t == 1) ? d1 : d2);
  int i = (blockIdx.x & 1023) * 256 + threadIdx.x;
#pragma unroll
  for (int u = 0; u < 8; ++u, i += 1024 * 256) {
    const float4 v = reinterpret_cast<const float4*>(s)[i];
    bf16x4 o;
    o[0] = (bf16_t)v.x; o[1] = (bf16_t)v.y; o[2] = (bf16_t)v.z; o[3] = (bf16_t)v.w;
    reinterpret_cast<bf16x4*>(d)[i] = o;
  }
}

__global__ __launch_bounds__(256) void cvt4_kernel(
    const float* __restrict__ s0, const float* __restrict__ s1,
    const float* __restrict__ s2, const float* __restrict__ s3,
    bf16_t* __restrict__ d0, bf16_t* __restrict__ d1,
    bf16_t* __restrict__ d2, bf16_t* __restrict__ d3) {
  const int t = blockIdx.x >> 7;
  const float* s = (t == 0) ? s0 : ((t == 1) ? s1 : ((t == 2) ? s2 : s3));
  bf16_t* d = (t == 0) ? d0 : ((t == 1) ? d1 : ((t == 2) ? d2 : d3));
  int i = (blockIdx.x & 127) * 256 + threadIdx.x;
#pragma unroll
  for (int u = 0; u < 8; ++u, i += 128 * 256) {
    const float4 v = reinterpret_cast<const float4*>(s)[i];
    bf16x4 o;
    o[0] = (bf16_t)v.x; o[1] = (bf16_t)v.y; o[2] = (bf16_t)v.z; o[3] = (bf16_t)v.w;
    reinterpret_cast<bf16x4*>(d)[i] = o;
  }
}

// ---------------- GEMM: Out = A @ W^T + bias ----------------
// MODE 0: Q -> [B,H,S,64] bf16, scaled by 0.125*log2e
// MODE 1: K -> [B,H,S,64] bf16
// MODE 2: V -> [B,H,64,S] bf16, k-columns SLOT-PERMUTED per 64-tile:
//         slot(k) = (k&32) | ((k&12)<<1) | ((k&16)>>2) | (k&3)
//         so attention's PV A-fragment == QK^T C-layout quads (no shuffle).
// MODE 3: O -> [M][N] fp32
#define GBM 128
#define GBN 128
#define GBK 32

template <int MODE>
__global__ __launch_bounds__(256) void gemm_bt(
    const bf16_t* __restrict__ A, const bf16_t* __restrict__ W,
    const float* __restrict__ bias, void* __restrict__ Out,
    int M, int N, int K) {
  __shared__ bf16_t As[GBM * GBK];
  __shared__ bf16_t Bs[GBN * GBK];
  const int tid = threadIdx.x;
  const int lane = tid & 63;
  const int w = tid >> 6;
  const int m0 = blockIdx.x * GBM;
  const int n0 = blockIdx.y * GBN;
  const int wm = (w >> 1) * 64;
  const int wn = (w & 1) * 64;

  f32x4 acc[4][4] = {};

  const int sr = w * 16 + (lane >> 2);
  const int sc = (lane & 3) * 8;
  const bf16_t* Ab = A + (size_t)(m0 + sr) * K + sc;
  const bf16_t* Wb = W + (size_t)(n0 + sr) * K + sc;
  const int rr = lane & 15;
  const int kk8 = (lane >> 4) * 8;

  for (int k0 = 0; k0 < K; k0 += GBK) {
    gld16(Ab + k0, &As[sr * GBK + sc]);
    gld16(Ab + (size_t)64 * K + k0, &As[(sr + 64) * GBK + sc]);
    gld16(Wb + k0, &Bs[sr * GBK + sc]);
    gld16(Wb + (size_t)64 * K + k0, &Bs[(sr + 64) * GBK + sc]);
    __syncthreads();
    bf16x8 a[4], b[4];
#pragma unroll
    for (int i = 0; i < 4; ++i)
      a[i] = *reinterpret_cast<const bf16x8*>(&As[(wm + i * 16 + rr) * GBK + kk8]);
#pragma unroll
    for (int i = 0; i < 4; ++i)
      b[i] = *reinterpret_cast<const bf16x8*>(&Bs[(wn + i * 16 + rr) * GBK + kk8]);
#pragma unroll
    for (int i = 0; i < 4; ++i)
#pragma unroll
      for (int j = 0; j < 4; ++j)
        acc[i][j] = __builtin_amdgcn_mfma_f32_16x16x32_bf16(a[i], b[j], acc[i][j], 0, 0, 0);
    __syncthreads();
  }

  const int rg = (lane >> 4) * 4;
#pragma unroll
  for (int i = 0; i < 4; ++i) {
#pragma unroll
    for (int j = 0; j < 4; ++j) {
      const int col = n0 + wn + j * 16 + rr;
      const float bi = bias[col];
      if (MODE == 3) {
#pragma unroll
        for (int r = 0; r < 4; ++r) {
          const int row = m0 + wm + i * 16 + rg + r;
          reinterpret_cast<float*>(Out)[(size_t)row * N + col] = acc[i][j][r] + bi;
        }
      } else if (MODE == 2) {
        const int row0 = m0 + wm + i * 16 + rg;
        const int b_ = row0 >> 11, s_ = row0 & 2047;
        const int h_ = col >> 6, d_ = col & 63;
        // slot-permute within the 64-tile (low 2 bits of s_ are 0 here)
        const int k64 = s_ & 63;
        const int sl = (k64 & 32) | ((k64 & 12) << 1) | ((k64 & 16) >> 2);
        const int scol = (s_ & ~63) | sl;
        bf16x4 pack;
#pragma unroll
        for (int r = 0; r < 4; ++r) pack[r] = (bf16_t)(acc[i][j][r] + bi);
        bf16_t* O = reinterpret_cast<bf16_t*>(Out);
        *reinterpret_cast<bf16x4*>(&O[((size_t)((b_ * 16 + h_) * 64 + d_)) * 2048 + scol]) = pack;
      } else {
#pragma unroll
        for (int r = 0; r < 4; ++r) {
          const int row = m0 + wm + i * 16 + rg + r;
          const int b_ = row >> 11, s_ = row & 2047;
          const int h_ = col >> 6, d_ = col & 63;
          float v = acc[i][j][r] + bi;
          if (MODE == 0) v *= 0.125f * LOG2E;
          bf16_t* O = reinterpret_cast<bf16_t*>(Out);
          O[((size_t)((b_ * 16 + h_) * 2048 + s_)) * 64 + d_] = (bf16_t)v;
        }
      }
    }
  }
}

// ---------------- flash attention with banded local bias ----------------
// v5: P never touches LDS. V's k-columns are slot-permuted (V-GEMM epilogue)
// so the PV A-fragment at lane (hi,rr) is exactly the QK^T output quads:
//   a[kk] = { sc[2kk][0..3], sc[2kk+1][0..3] }  (bf16-converted in-register).
// Removes 8 ds_write + 4 ds_read + lgkmcnt(0) serialization per k-tile.
#define QT 128
#define KT 64

__global__ __launch_bounds__(256) void attn_kernel(
    const bf16_t* __restrict__ Qg, const bf16_t* __restrict__ Kg,
    const bf16_t* __restrict__ Vtg, const float* __restrict__ lb,
    bf16_t* __restrict__ Og) {
  const int S = 2048;
  __shared__ bf16_t Qs[QT * 64];   // 16KB, swizzled (prologue only)
  __shared__ bf16_t Ks[KT * 64];   // 8KB, swizzled
  __shared__ bf16_t Vts[64 * KT];  // 8KB, swizzled (rows=d, cols=k-slots)
  __shared__ float lbs[33];

  const int tid = threadIdx.x, lane = tid & 63, w = tid >> 6;
  const int qt0 = blockIdx.x * QT;
  const int bh = blockIdx.y;
  const int b_ = bh >> 4, h_ = bh & 15;

  const char* Qb = (const char*)(Qg + (size_t)bh * S * 64);
  const char* Kb = (const char*)(Kg + (size_t)bh * S * 64);
  const char* Vtb = (const char*)(Vtg + (size_t)bh * 64 * S);

  const int loff = w * 1024 + lane * 16;
#pragma unroll
  for (int i = 0; i < 4; ++i) {
    const int off = i * 4096 + loff;
    gld16(Qb + (size_t)qt0 * 128 + swz(off), (char*)Qs + off);
  }
  if (tid < 33) lbs[tid] = lb[tid];

  // T14 staging: per-thread 16B chunks; write-side swizzle
  const int L0 = tid * 16;                   // 0..4095
  const int W0 = swz(L0), W1 = swz(L0 + 4096);
  const int vd0 = L0 >> 7, vcb = L0 & 127;   // Vt row/col for chunk 0
  int4 kr0, kr1, vr0, vr1;
  {
    kr0 = *reinterpret_cast<const int4*>(Kb + L0);
    kr1 = *reinterpret_cast<const int4*>(Kb + L0 + 4096);
    vr0 = *reinterpret_cast<const int4*>(Vtb + (size_t)vd0 * 4096 + vcb);
    vr1 = *reinterpret_cast<const int4*>(Vtb + (size_t)(vd0 + 32) * 4096 + vcb);
  }
  __syncthreads();  // Q staged (drains gld16)

  const int rr = lane & 15;
  const int kk8 = (lane >> 4) * 8;
  const int rg = (lane >> 4) * 4;

  bf16x8 qf[2][2];
#pragma unroll
  for (int qg = 0; qg < 2; ++qg)
#pragma unroll
    for (int kk = 0; kk < 2; ++kk) {
      const int off = (w * 32 + qg * 16 + rr) * 128 + (kk * 32 + kk8) * 2;
      qf[qg][kk] = *reinterpret_cast<const bf16x8*>((const char*)Qs + swz(off));
    }

  f32x4 oacc[2][4] = {};
  float lrowp[2] = {0.f, 0.f};

  for (int kt = 0; kt < S / KT; ++kt) {
    // write staged tile kt to LDS (regs loaded last iter; latency hidden)
    *reinterpret_cast<int4*>((char*)Ks + W0) = kr0;
    *reinterpret_cast<int4*>((char*)Ks + W1) = kr1;
    *reinterpret_cast<int4*>((char*)Vts + W0) = vr0;
    *reinterpret_cast<int4*>((char*)Vts + W1) = vr1;
    // prefetch tile kt+1 (clamped; overlaps this iteration's compute)
    {
      const int ktn = (kt + 1) & 31;
      const char* kp = Kb + (size_t)ktn * 8192;
      kr0 = *reinterpret_cast<const int4*>(kp + L0);
      kr1 = *reinterpret_cast<const int4*>(kp + L0 + 4096);
      const char* vp = Vtb + (size_t)ktn * 128;
      vr0 = *reinterpret_cast<const int4*>(vp + (size_t)vd0 * 4096 + vcb);
      vr1 = *reinterpret_cast<const int4*>(vp + (size_t)(vd0 + 32) * 4096 + vcb);
    }
    __syncthreads();  // tile kt visible

    // QK^T (swapped): lane holds q = qg*16+rr, k = 16*ni + 4*hi + r
    bf16x8 kf[4][2];
#pragma unroll
    for (int ni = 0; ni < 4; ++ni)
#pragma unroll
      for (int kk = 0; kk < 2; ++kk) {
        const int off = (ni * 16 + rr) * 128 + (kk * 32 + kk8) * 2;
        kf[ni][kk] = *reinterpret_cast<const bf16x8*>((const char*)Ks + swz(off));
      }
    f32x4 sc[2][4];
    __builtin_amdgcn_s_setprio(1);
#pragma unroll
    for (int qg = 0; qg < 2; ++qg)
#pragma unroll
      for (int ni = 0; ni < 4; ++ni) {
        f32x4 z = {0.f, 0.f, 0.f, 0.f};
#pragma unroll
        for (int kk = 0; kk < 2; ++kk)
          z = __builtin_amdgcn_mfma_f32_16x16x32_bf16(kf[ni][kk], qf[qg][kk], z, 0, 0, 0);
        sc[qg][ni] = z;
      }
    __builtin_amdgcn_s_setprio(0);

    // banded local bias (exp2 domain)
    const int kbase = kt * KT;
    if (kbase + KT + 16 > qt0 && kbase < qt0 + QT + 16) {
#pragma unroll
      for (int qg = 0; qg < 2; ++qg) {
        const int q = qt0 + w * 32 + qg * 16 + rr;
#pragma unroll
        for (int ni = 0; ni < 4; ++ni)
#pragma unroll
          for (int r = 0; r < 4; ++r) {
            const int rel = (kbase + ni * 16 + rg + r) - q;
            if (rel >= -16 && rel <= 16)
              sc[qg][ni][r] += (2.0f * LOG2E) * lbs[rel + 16];
          }
      }
    }

    // softmax (no max subtraction; scores bounded) + PV A-frags in-register
    bf16x8 paf[2][2];
#pragma unroll
    for (int qg = 0; qg < 2; ++qg) {
      float ps0 = 0.f, ps1 = 0.f;
#pragma unroll
      for (int ni = 0; ni < 4; ++ni) {
        const float p0 = exp2f(sc[qg][ni][0]);
        const float p1 = exp2f(sc[qg][ni][1]);
        const float p2 = exp2f(sc[qg][ni][2]);
        const float p3 = exp2f(sc[qg][ni][3]);
        ps0 += p0 + p2;
        ps1 += p1 + p3;
        paf[qg][ni >> 1][(ni & 1) * 4 + 0] = (bf16_t)p0;
        paf[qg][ni >> 1][(ni & 1) * 4 + 1] = (bf16_t)p1;
        paf[qg][ni >> 1][(ni & 1) * 4 + 2] = (bf16_t)p2;
        paf[qg][ni >> 1][(ni & 1) * 4 + 3] = (bf16_t)p3;
      }
      lrowp[qg] += ps0 + ps1;
    }

    // V B-frags (slot space matches A-frag slots by construction)
    bf16x8 vf[2][4];
#pragma unroll
    for (int kk = 0; kk < 2; ++kk)
#pragma unroll
      for (int nd = 0; nd < 4; ++nd) {
        const int off = (nd * 16 + rr) * 128 + (kk * 32 + kk8) * 2;
        vf[kk][nd] = *reinterpret_cast<const bf16x8*>((const char*)Vts + swz(off));
      }

    // PV
    __builtin_amdgcn_s_setprio(1);
#pragma unroll
    for (int kk = 0; kk < 2; ++kk)
#pragma unroll
      for (int qg = 0; qg < 2; ++qg)
#pragma unroll
        for (int nd = 0; nd < 4; ++nd)
          oacc[qg][nd] = __builtin_amdgcn_mfma_f32_16x16x32_bf16(paf[qg][kk], vf[kk][nd], oacc[qg][nd], 0, 0, 0);
    __builtin_amdgcn_s_setprio(0);
    __syncthreads();  // all waves done reading Ks/Vts before next ds_write
  }

  // epilogue: reduce l across the 4 lane-groups, then divide + store
  float lr[2];
#pragma unroll
  for (int qg = 0; qg < 2; ++qg) {
    float t = lrowp[qg];
    t += __shfl_xor(t, 16, 64);
    t += __shfl_xor(t, 32, 64);
    lr[qg] = t;
  }
#pragma unroll
  for (int mi = 0; mi < 2; ++mi) {
    float lf[4];
#pragma unroll
    for (int r = 0; r < 4; ++r)
      lf[r] = __shfl(lr[mi], (lane & 48) | (rg + r), 64);
#pragma unroll
    for (int nd = 0; nd < 4; ++nd)
#pragma unroll
      for (int r = 0; r < 4; ++r) {
        const int srow = qt0 + w * 32 + mi * 16 + rg + r;
        const int d = nd * 16 + rr;
        const float v = oacc[mi][nd][r] / lf[r];
        Og[((size_t)(b_ * 2048 + srow)) * 1024 + h_ * 64 + d] = (bf16_t)v;
      }
  }
}

// ---------------- launch ----------------
extern "C" void kernel_launch(void* const* d_in, const int* in_sizes, int n_in,
                              void* d_out, int out_size, void* d_ws, size_t ws_size,
                              hipStream_t stream) {
  const float* q32 = (const float*)d_in[0];
  const float* k32 = (const float*)d_in[1];
  const float* v32 = (const float*)d_in[2];
  const float* wq = (const float*)d_in[3];
  const float* bq = (const float*)d_in[4];
  const float* wk = (const float*)d_in[5];
  const float* bk = (const float*)d_in[6];
  const float* wv = (const float*)d_in[7];
  const float* bv = (const float*)d_in[8];
  const float* wo = (const float*)d_in[9];
  const float* bo = (const float*)d_in[10];
  const float* lb = (const float*)d_in[11];

  const int M = 8192, N = 1024, K = 1024;
  const size_t REG = (size_t)M * N * 2;

  char* ws = (char*)d_ws;
  bf16_t* Xq = (bf16_t*)(ws + 0 * REG);
  bf16_t* Xk = (bf16_t*)(ws + 1 * REG);
  bf16_t* Xv = (bf16_t*)(ws + 2 * REG);
  bf16_t* Qb = (bf16_t*)(ws + 3 * REG);
  bf16_t* Wqb = (bf16_t*)(ws + 4 * REG);
  bf16_t* Wkb = Wqb + (size_t)N * K;
  bf16_t* Wvb = Wkb + (size_t)N * K;
  bf16_t* Wob = Wvb + (size_t)N * K;
  bf16_t* Kb = Xq;    // Xq dead after Q-GEMM
  bf16_t* Vt = Xk;    // Xk dead after K-GEMM
  bf16_t* attn = Xv;  // Xv dead after V-GEMM

  cvt3_kernel<<<dim3(3072), dim3(256), 0, stream>>>(q32, k32, v32, Xq, Xk, Xv);
  cvt4_kernel<<<dim3(512), dim3(256), 0, stream>>>(wq, wk, wv, wo, Wqb, Wkb, Wvb, Wob);

  dim3 gg(M / GBM, N / GBN);
  gemm_bt<0><<<gg, 256, 0, stream>>>(Xq, Wqb, bq, Qb, M, N, K);
  gemm_bt<1><<<gg, 256, 0, stream>>>(Xk, Wkb, bk, Kb, M, N, K);
  gemm_bt<2><<<gg, 256, 0, stream>>>(Xv, Wvb, bv, Vt, M, N, K);

  attn_kernel<<<dim3(2048 / QT, 64), 256, 0, stream>>>(Qb, Kb, Vt, lb, attn);

  gemm_bt<3><<<gg, 256, 0, stream>>>(attn, Wob, bo, d_out, M, N, K);
}

// Round 6
// 247.972 us; speedup vs baseline: 1.1513x; 1.1262x over previous
//
#include <hip/hip_runtime.h>
#include <hip/hip_bf16.h>
#include <stdint.h>

typedef __bf16 bf16_t;
typedef bf16_t bf16x8 __attribute__((ext_vector_type(8)));
typedef bf16_t bf16x4 __attribute__((ext_vector_type(4)));
typedef float f32x4 __attribute__((ext_vector_type(4)));

#define LOG2E 1.44269504088896340736f

// async global->LDS, 16B per lane. Dest must be linear (base + lane*16).
__device__ __forceinline__ void gld16(const void* g, void* l) {
  __builtin_amdgcn_global_load_lds(
      (__attribute__((address_space(1))) void*)(void*)(g),
      (__attribute__((address_space(3))) void*)(l), 16, 0, 0);
}

// XOR swizzle for 128B-row LDS tiles: spreads the 16B column slots across rows.
__device__ __forceinline__ int swz(int byteoff) {
  return byteoff ^ (((byteoff >> 7) & 7) << 4);
}

// ---------------- fp32 -> bf16 convert: ALL 7 tensors in one launch ----------
// blocks [0,3072): activations (3 x 1024 blocks, 2^21 float4 each)
// blocks [3072,3584): weights (4 x 128 blocks, 2^18 float4 each)
__global__ __launch_bounds__(256) void cvt7_kernel(
    const float* __restrict__ a0, const float* __restrict__ a1, const float* __restrict__ a2,
    const float* __restrict__ w0, const float* __restrict__ w1,
    const float* __restrict__ w2, const float* __restrict__ w3,
    bf16_t* __restrict__ e0, bf16_t* __restrict__ e1, bf16_t* __restrict__ e2,
    bf16_t* __restrict__ f0, bf16_t* __restrict__ f1,
    bf16_t* __restrict__ f2, bf16_t* __restrict__ f3) {
  const float* s;
  bf16_t* d;
  int i, stride;
  if (blockIdx.x < 3072) {
    const int t = blockIdx.x >> 10;
    s = (t == 0) ? a0 : ((t == 1) ? a1 : a2);
    d = (t == 0) ? e0 : ((t == 1) ? e1 : e2);
    i = (blockIdx.x & 1023) * 256 + threadIdx.x;
    stride = 1024 * 256;
  } else {
    const int b = blockIdx.x - 3072;
    const int t = b >> 7;
    s = (t == 0) ? w0 : ((t == 1) ? w1 : ((t == 2) ? w2 : w3));
    d = (t == 0) ? f0 : ((t == 1) ? f1 : ((t == 2) ? f2 : f3));
    i = (b & 127) * 256 + threadIdx.x;
    stride = 128 * 256;
  }
#pragma unroll
  for (int u = 0; u < 8; ++u, i += stride) {
    const float4 v = reinterpret_cast<const float4*>(s)[i];
    bf16x4 o;
    o[0] = (bf16_t)v.x; o[1] = (bf16_t)v.y; o[2] = (bf16_t)v.z; o[3] = (bf16_t)v.w;
    reinterpret_cast<bf16x4*>(d)[i] = o;
  }
}

// ---------------- fused Q/K/V projection GEMMs (blockIdx.z selects) --------
// z=0: Q -> [B,H,S,64] scaled by 0.125*log2e
// z=1: K -> [B,H,S,64]
// z=2: V -> [B,H,64,S], k-columns slot-permuted per 64-tile:
//      slot(k) = (k&32) | ((k&12)<<1) | ((k&16)>>2) | (k&3)
#define GBM 128
#define GBN 128
#define GBK 32

__global__ __launch_bounds__(256) void gemm_qkv(
    const bf16_t* __restrict__ Xq, const bf16_t* __restrict__ Xk, const bf16_t* __restrict__ Xv,
    const bf16_t* __restrict__ Wq, const bf16_t* __restrict__ Wk, const bf16_t* __restrict__ Wv,
    const float* __restrict__ bq, const float* __restrict__ bk, const float* __restrict__ bv,
    bf16_t* __restrict__ Qo, bf16_t* __restrict__ Ko, bf16_t* __restrict__ Vo,
    int M, int N, int K) {
  const int z = blockIdx.z;
  const bf16_t* A = (z == 0) ? Xq : ((z == 1) ? Xk : Xv);
  const bf16_t* W = (z == 0) ? Wq : ((z == 1) ? Wk : Wv);
  const float* bias = (z == 0) ? bq : ((z == 1) ? bk : bv);
  bf16_t* Out = (z == 0) ? Qo : ((z == 1) ? Ko : Vo);

  __shared__ bf16_t As[GBM * GBK];
  __shared__ bf16_t Bs[GBN * GBK];
  const int tid = threadIdx.x;
  const int lane = tid & 63;
  const int w = tid >> 6;
  const int m0 = blockIdx.x * GBM;
  const int n0 = blockIdx.y * GBN;
  const int wm = (w >> 1) * 64;
  const int wn = (w & 1) * 64;

  f32x4 acc[4][4] = {};

  const int sr = w * 16 + (lane >> 2);
  const int sc = (lane & 3) * 8;
  const bf16_t* Ab = A + (size_t)(m0 + sr) * K + sc;
  const bf16_t* Wb = W + (size_t)(n0 + sr) * K + sc;
  const int rr = lane & 15;
  const int kk8 = (lane >> 4) * 8;

  for (int k0 = 0; k0 < K; k0 += GBK) {
    gld16(Ab + k0, &As[sr * GBK + sc]);
    gld16(Ab + (size_t)64 * K + k0, &As[(sr + 64) * GBK + sc]);
    gld16(Wb + k0, &Bs[sr * GBK + sc]);
    gld16(Wb + (size_t)64 * K + k0, &Bs[(sr + 64) * GBK + sc]);
    __syncthreads();
    bf16x8 a[4], b[4];
#pragma unroll
    for (int i = 0; i < 4; ++i)
      a[i] = *reinterpret_cast<const bf16x8*>(&As[(wm + i * 16 + rr) * GBK + kk8]);
#pragma unroll
    for (int i = 0; i < 4; ++i)
      b[i] = *reinterpret_cast<const bf16x8*>(&Bs[(wn + i * 16 + rr) * GBK + kk8]);
#pragma unroll
    for (int i = 0; i < 4; ++i)
#pragma unroll
      for (int j = 0; j < 4; ++j)
        acc[i][j] = __builtin_amdgcn_mfma_f32_16x16x32_bf16(a[i], b[j], acc[i][j], 0, 0, 0);
    __syncthreads();
  }

  const int rg = (lane >> 4) * 4;
#pragma unroll
  for (int i = 0; i < 4; ++i) {
#pragma unroll
    for (int j = 0; j < 4; ++j) {
      const int col = n0 + wn + j * 16 + rr;
      const float bi = bias[col];
      if (z == 2) {
        const int row0 = m0 + wm + i * 16 + rg;
        const int b_ = row0 >> 11, s_ = row0 & 2047;
        const int h_ = col >> 6, d_ = col & 63;
        const int k64 = s_ & 63;
        const int sl = (k64 & 32) | ((k64 & 12) << 1) | ((k64 & 16) >> 2);
        const int scol = (s_ & ~63) | sl;
        bf16x4 pack;
#pragma unroll
        for (int r = 0; r < 4; ++r) pack[r] = (bf16_t)(acc[i][j][r] + bi);
        *reinterpret_cast<bf16x4*>(&Out[((size_t)((b_ * 16 + h_) * 64 + d_)) * 2048 + scol]) = pack;
      } else {
        const float scale = (z == 0) ? (0.125f * LOG2E) : 1.0f;
#pragma unroll
        for (int r = 0; r < 4; ++r) {
          const int row = m0 + wm + i * 16 + rg + r;
          const int b_ = row >> 11, s_ = row & 2047;
          const int h_ = col >> 6, d_ = col & 63;
          Out[((size_t)((b_ * 16 + h_) * 2048 + s_)) * 64 + d_] = (bf16_t)((acc[i][j][r] + bi) * scale);
        }
      }
    }
  }
}

// ---------------- output projection GEMM: fp32 out ----------------
__global__ __launch_bounds__(256) void gemm_o(
    const bf16_t* __restrict__ A, const bf16_t* __restrict__ W,
    const float* __restrict__ bias, float* __restrict__ Out,
    int M, int N, int K) {
  __shared__ bf16_t As[GBM * GBK];
  __shared__ bf16_t Bs[GBN * GBK];
  const int tid = threadIdx.x;
  const int lane = tid & 63;
  const int w = tid >> 6;
  const int m0 = blockIdx.x * GBM;
  const int n0 = blockIdx.y * GBN;
  const int wm = (w >> 1) * 64;
  const int wn = (w & 1) * 64;

  f32x4 acc[4][4] = {};

  const int sr = w * 16 + (lane >> 2);
  const int sc = (lane & 3) * 8;
  const bf16_t* Ab = A + (size_t)(m0 + sr) * K + sc;
  const bf16_t* Wb = W + (size_t)(n0 + sr) * K + sc;
  const int rr = lane & 15;
  const int kk8 = (lane >> 4) * 8;

  for (int k0 = 0; k0 < K; k0 += GBK) {
    gld16(Ab + k0, &As[sr * GBK + sc]);
    gld16(Ab + (size_t)64 * K + k0, &As[(sr + 64) * GBK + sc]);
    gld16(Wb + k0, &Bs[sr * GBK + sc]);
    gld16(Wb + (size_t)64 * K + k0, &Bs[(sr + 64) * GBK + sc]);
    __syncthreads();
    bf16x8 a[4], b[4];
#pragma unroll
    for (int i = 0; i < 4; ++i)
      a[i] = *reinterpret_cast<const bf16x8*>(&As[(wm + i * 16 + rr) * GBK + kk8]);
#pragma unroll
    for (int i = 0; i < 4; ++i)
      b[i] = *reinterpret_cast<const bf16x8*>(&Bs[(wn + i * 16 + rr) * GBK + kk8]);
#pragma unroll
    for (int i = 0; i < 4; ++i)
#pragma unroll
      for (int j = 0; j < 4; ++j)
        acc[i][j] = __builtin_amdgcn_mfma_f32_16x16x32_bf16(a[i], b[j], acc[i][j], 0, 0, 0);
    __syncthreads();
  }

  const int rg = (lane >> 4) * 4;
#pragma unroll
  for (int i = 0; i < 4; ++i)
#pragma unroll
    for (int j = 0; j < 4; ++j) {
      const int col = n0 + wn + j * 16 + rr;
      const float bi = bias[col];
#pragma unroll
      for (int r = 0; r < 4; ++r) {
        const int row = m0 + wm + i * 16 + rg + r;
        Out[(size_t)row * N + col] = acc[i][j][r] + bi;
      }
    }
}

// ---------------- flash attention with banded local bias ----------------
// v6: QT=256 (wave owns 64 q-rows, qg 0..3) -> K/V LDS + VMEM traffic per
// q-row HALVED vs v5. P stays in registers (slot-permuted V). Grid (8,64)
// = 512 blocks = 2/CU (R4 showed extra waves buy nothing; traffic wins).
#define QT 256
#define KT 64

__global__ __launch_bounds__(256, 2) void attn_kernel(
    const bf16_t* __restrict__ Qg, const bf16_t* __restrict__ Kg,
    const bf16_t* __restrict__ Vtg, const float* __restrict__ lb,
    bf16_t* __restrict__ Og) {
  const int S = 2048;
  __shared__ bf16_t Qs[QT * 64];   // 32KB, swizzled (prologue only)
  __shared__ bf16_t Ks[KT * 64];   // 8KB, swizzled
  __shared__ bf16_t Vts[64 * KT];  // 8KB, swizzled (rows=d, cols=k-slots)
  __shared__ float lbs[33];

  const int tid = threadIdx.x, lane = tid & 63, w = tid >> 6;
  const int qt0 = blockIdx.x * QT;
  const int bh = blockIdx.y;
  const int b_ = bh >> 4, h_ = bh & 15;

  const char* Qb = (const char*)(Qg + (size_t)bh * S * 64);
  const char* Kb = (const char*)(Kg + (size_t)bh * S * 64);
  const char* Vtb = (const char*)(Vtg + (size_t)bh * 64 * S);

  // stage Q tile: 32KB = 8 issues x 256 threads x 16B
#pragma unroll
  for (int i = 0; i < 8; ++i) {
    const int off = i * 4096 + tid * 16;
    gld16(Qb + (size_t)qt0 * 128 + swz(off), (char*)Qs + off);
  }
  if (tid < 33) lbs[tid] = lb[tid];

  // K/V reg staging (T14), write-side swizzle
  const int L0 = tid * 16;                   // 0..4095
  const int W0 = swz(L0), W1 = swz(L0 + 4096);
  const int vd0 = L0 >> 7, vcb = L0 & 127;
  int4 kr0, kr1, vr0, vr1;
  {
    kr0 = *reinterpret_cast<const int4*>(Kb + L0);
    kr1 = *reinterpret_cast<const int4*>(Kb + L0 + 4096);
    vr0 = *reinterpret_cast<const int4*>(Vtb + (size_t)vd0 * 4096 + vcb);
    vr1 = *reinterpret_cast<const int4*>(Vtb + (size_t)(vd0 + 32) * 4096 + vcb);
  }
  __syncthreads();  // Q staged (drains gld16)

  const int rr = lane & 15;
  const int kk8 = (lane >> 4) * 8;
  const int rg = (lane >> 4) * 4;

  bf16x8 qf[4][2];  // wave w owns q rows [w*64, w*64+64)
#pragma unroll
  for (int qg = 0; qg < 4; ++qg)
#pragma unroll
    for (int kk = 0; kk < 2; ++kk) {
      const int off = (w * 64 + qg * 16 + rr) * 128 + (kk * 32 + kk8) * 2;
      qf[qg][kk] = *reinterpret_cast<const bf16x8*>((const char*)Qs + swz(off));
    }

  f32x4 oacc[4][4] = {};
  float lrowp[4] = {0.f, 0.f, 0.f, 0.f};

  for (int kt = 0; kt < S / KT; ++kt) {
    // commit staged tile kt
    *reinterpret_cast<int4*>((char*)Ks + W0) = kr0;
    *reinterpret_cast<int4*>((char*)Ks + W1) = kr1;
    *reinterpret_cast<int4*>((char*)Vts + W0) = vr0;
    *reinterpret_cast<int4*>((char*)Vts + W1) = vr1;
    // prefetch tile kt+1
    {
      const int ktn = (kt + 1) & 31;
      const char* kp = Kb + (size_t)ktn * 8192;
      kr0 = *reinterpret_cast<const int4*>(kp + L0);
      kr1 = *reinterpret_cast<const int4*>(kp + L0 + 4096);
      const char* vp = Vtb + (size_t)ktn * 128;
      vr0 = *reinterpret_cast<const int4*>(vp + (size_t)vd0 * 4096 + vcb);
      vr1 = *reinterpret_cast<const int4*>(vp + (size_t)(vd0 + 32) * 4096 + vcb);
    }
    __syncthreads();  // tile kt visible

    bf16x8 kf[4][2];
#pragma unroll
    for (int ni = 0; ni < 4; ++ni)
#pragma unroll
      for (int kk = 0; kk < 2; ++kk) {
        const int off = (ni * 16 + rr) * 128 + (kk * 32 + kk8) * 2;
        kf[ni][kk] = *reinterpret_cast<const bf16x8*>((const char*)Ks + swz(off));
      }
    bf16x8 vf[2][4];
#pragma unroll
    for (int kk = 0; kk < 2; ++kk)
#pragma unroll
      for (int nd = 0; nd < 4; ++nd) {
        const int off = (nd * 16 + rr) * 128 + (kk * 32 + kk8) * 2;
        vf[kk][nd] = *reinterpret_cast<const bf16x8*>((const char*)Vts + swz(off));
      }

    const int kbase = kt * KT;
#pragma unroll
    for (int qg = 0; qg < 4; ++qg) {
      // QK^T (swapped): lane holds q = w*64 + qg*16 + rr; k = 16ni + 4hi + r
      f32x4 sc[4];
      __builtin_amdgcn_s_setprio(1);
#pragma unroll
      for (int ni = 0; ni < 4; ++ni) {
        f32x4 z = {0.f, 0.f, 0.f, 0.f};
#pragma unroll
        for (int kk = 0; kk < 2; ++kk)
          z = __builtin_amdgcn_mfma_f32_16x16x32_bf16(kf[ni][kk], qf[qg][kk], z, 0, 0, 0);
        sc[ni] = z;
      }
      __builtin_amdgcn_s_setprio(0);

      // banded local bias (exp2 domain); wave-uniform guard per qg
      const int qlo = qt0 + w * 64 + qg * 16;
      if (kbase + KT + 16 > qlo && kbase < qlo + 16 + 16) {
        const int q = qlo + rr;
#pragma unroll
        for (int ni = 0; ni < 4; ++ni)
#pragma unroll
          for (int r = 0; r < 4; ++r) {
            const int rel = (kbase + ni * 16 + rg + r) - q;
            if (rel >= -16 && rel <= 16)
              sc[ni][r] += (2.0f * LOG2E) * lbs[rel + 16];
          }
      }

      // softmax (no max subtraction; scores bounded) + PV A-frags in-register
      bf16x8 paf[2];
      float ps0 = 0.f, ps1 = 0.f;
#pragma unroll
      for (int ni = 0; ni < 4; ++ni) {
        const float p0 = exp2f(sc[ni][0]);
        const float p1 = exp2f(sc[ni][1]);
        const float p2 = exp2f(sc[ni][2]);
        const float p3 = exp2f(sc[ni][3]);
        ps0 += p0 + p2;
        ps1 += p1 + p3;
        paf[ni >> 1][(ni & 1) * 4 + 0] = (bf16_t)p0;
        paf[ni >> 1][(ni & 1) * 4 + 1] = (bf16_t)p1;
        paf[ni >> 1][(ni & 1) * 4 + 2] = (bf16_t)p2;
        paf[ni >> 1][(ni & 1) * 4 + 3] = (bf16_t)p3;
      }
      lrowp[qg] += ps0 + ps1;

      // PV (V slot-permuted to match A-frag slots)
      __builtin_amdgcn_s_setprio(1);
#pragma unroll
      for (int kk = 0; kk < 2; ++kk)
#pragma unroll
        for (int nd = 0; nd < 4; ++nd)
          oacc[qg][nd] = __builtin_amdgcn_mfma_f32_16x16x32_bf16(paf[kk], vf[kk][nd], oacc[qg][nd], 0, 0, 0);
      __builtin_amdgcn_s_setprio(0);
    }
    __syncthreads();  // all waves done reading Ks/Vts before next ds_write
  }

  // epilogue
#pragma unroll
  for (int qg = 0; qg < 4; ++qg) {
    float t = lrowp[qg];
    t += __shfl_xor(t, 16, 64);
    t += __shfl_xor(t, 32, 64);
    float lf[4];
#pragma unroll
    for (int r = 0; r < 4; ++r)
      lf[r] = __shfl(t, (lane & 48) | (rg + r), 64);
#pragma unroll
    for (int nd = 0; nd < 4; ++nd)
#pragma unroll
      for (int r = 0; r < 4; ++r) {
        const int srow = qt0 + w * 64 + qg * 16 + rg + r;
        const int d = nd * 16 + rr;
        const float v = oacc[qg][nd][r] / lf[r];
        Og[((size_t)(b_ * 2048 + srow)) * 1024 + h_ * 64 + d] = (bf16_t)v;
      }
  }
}

// ---------------- launch ----------------
extern "C" void kernel_launch(void* const* d_in, const int* in_sizes, int n_in,
                              void* d_out, int out_size, void* d_ws, size_t ws_size,
                              hipStream_t stream) {
  const float* q32 = (const float*)d_in[0];
  const float* k32 = (const float*)d_in[1];
  const float* v32 = (const float*)d_in[2];
  const float* wq = (const float*)d_in[3];
  const float* bq = (const float*)d_in[4];
  const float* wk = (const float*)d_in[5];
  const float* bk = (const float*)d_in[6];
  const float* wv = (const float*)d_in[7];
  const float* bv = (const float*)d_in[8];
  const float* wo = (const float*)d_in[9];
  const float* bo = (const float*)d_in[10];
  const float* lb = (const float*)d_in[11];

  const int M = 8192, N = 1024, K = 1024;
  const size_t REG = (size_t)M * N * 2;

  char* ws = (char*)d_ws;
  bf16_t* Xq = (bf16_t*)(ws + 0 * REG);
  bf16_t* Xk = (bf16_t*)(ws + 1 * REG);
  bf16_t* Xv = (bf16_t*)(ws + 2 * REG);
  bf16_t* Qb = (bf16_t*)(ws + 3 * REG);
  bf16_t* Wqb = (bf16_t*)(ws + 4 * REG);
  bf16_t* Wkb = Wqb + (size_t)N * K;
  bf16_t* Wvb = Wkb + (size_t)N * K;
  bf16_t* Wob = Wvb + (size_t)N * K;
  bf16_t* Kb = Xq;    // Xq dead after Q-GEMM
  bf16_t* Vt = Xk;    // Xk dead after K-GEMM
  bf16_t* attn = Xv;  // Xv dead after V-GEMM

  cvt7_kernel<<<dim3(3584), dim3(256), 0, stream>>>(
      q32, k32, v32, wq, wk, wv, wo, Xq, Xk, Xv, Wqb, Wkb, Wvb, Wob);

  gemm_qkv<<<dim3(M / GBM, N / GBN, 3), 256, 0, stream>>>(
      Xq, Xk, Xv, Wqb, Wkb, Wvb, bq, bk, bv, Qb, Kb, Vt, M, N, K);

  attn_kernel<<<dim3(2048 / QT, 64), 256, 0, stream>>>(Qb, Kb, Vt, lb, attn);

  gemm_o<<<dim3(M / GBM, N / GBN), 256, 0, stream>>>(attn, Wob, bo, (float*)d_out, M, N, K);
}